// Round 17
// baseline (329.336 us; speedup 1.0000x reference)
//
#include <hip/hip_runtime.h>
#include <hip/hip_bf16.h>
#include <stdint.h>

// ElementReadoutMLP: species-routed 2-layer MLP, fused.
// r17: BARRIER-FREE wave-autonomous gemm with a spill-proof register budget.
// (r13/r14 proved this structure correct but died on register spills; r17
// caps live state at af[8]=32 + acc[16]=64 VGPRs.)
//   bhist_k / scan_k / dscatter_k : countsort atoms by species;
//     scan_k partitions gemm blocks across species by 16-atom GROUPS.
//   convw_k : W1 -> pre-swizzled bf16 wt (LDS-image layout, coalesced)
//   gemm_k  : 256 blocks x 512 thr, ONE species per block.  Whole W1[e]
//             (128KB bf16) -> LDS once; ONE barrier; then each wave
//             independently processes 16-atom groups: x -> reg frags (cvt
//             once), 128 ds_read_b128 + 128 swapped MFMAs (D[n][atom]),
//             in-lane SiLU+w2 fold, 2 shfl_xor, store.  ZERO barriers and
//             zero LDS staging in the grind loop.

#define NDIM 256
#define CHUNKS 16      // scan chunks per species (NE*CHUNKS <= 256)
#define BCHUNK 16384   // bytes per W k-chunk (256 n x 32 k x 2B)
#define GRP 16         // atoms per group (one wave-iteration)
#define NB_GEMM 256    // persistent gemm grid (1 block/CU)

typedef __attribute__((ext_vector_type(8))) short short8;
typedef __attribute__((ext_vector_type(8))) unsigned short ushort8;
typedef __attribute__((ext_vector_type(4))) float f32x4;

__device__ __forceinline__ unsigned short f2bf(float f) {
  unsigned u = __float_as_uint(f);
  u = (u + 0x7FFFu + ((u >> 16) & 1u)) >> 16;   // round-to-nearest-even
  return (unsigned short)u;
}

// async global->LDS, 16B per lane; lds dest wave-uniform base (+lane*16 HW).
__device__ __forceinline__ void gload_lds16(const void* gsrc, void* ldst) {
  __builtin_amdgcn_global_load_lds(
      (const __attribute__((address_space(1))) unsigned*)gsrc,
      (__attribute__((address_space(3))) unsigned*)(uintptr_t)(unsigned)(uintptr_t)ldst,
      16, 0, 0);
}

// pack 8 fp32 -> short8 of bf16 (RNE, packed cvt)
__device__ __forceinline__ short8 cvt8(f32x4 lo, f32x4 hi) {
  union { short8 s; unsigned u[4]; } r;
  __hip_bfloat162 t;
  t = __float22bfloat162_rn(make_float2(lo[0], lo[1])); r.u[0] = *(unsigned*)&t;
  t = __float22bfloat162_rn(make_float2(lo[2], lo[3])); r.u[1] = *(unsigned*)&t;
  t = __float22bfloat162_rn(make_float2(hi[0], hi[1])); r.u[2] = *(unsigned*)&t;
  t = __float22bfloat162_rn(make_float2(hi[2], hi[3])); r.u[3] = *(unsigned*)&t;
  return r.s;
}

// ---- prep kernels -----------------------------------------------------------

// wt layout: chunk(e,step) = wt + (e*8+step)*BCHUNK bytes; within chunk,
// bf16 for (n,kk) at byte ((n*64 + kk*2) ^ ((n&7)<<4)).  Linear copy into
// LDS reproduces the swizzled layout gemm_k's ds_reads expect (rule #21).
__global__ void convw_k(const float* __restrict__ W1, unsigned short* __restrict__ wt, int NE) {
  __shared__ float ldsW[32 * 260];   // 32 k-rows x 256 n, padded
  int blk = blockIdx.x;              // e*8 + step
  int e = blk >> 3, step = blk & 7;
  int tid = threadIdx.x;
  int k0 = step * 32;
  {
    int kk = tid >> 3, part = tid & 7;
    const float* src = W1 + ((size_t)e << 16) + (size_t)(k0 + kk) * NDIM + part * 32;
    #pragma unroll
    for (int j = 0; j < 8; ++j) {
      f32x4 v = *(const f32x4*)(src + j * 4);
      *(f32x4*)&ldsW[kk * 260 + part * 32 + j * 4] = v;
    }
  }
  __syncthreads();
  {
    int n = tid;
    unsigned short v[32];
    #pragma unroll
    for (int kk = 0; kk < 32; ++kk) v[kk] = f2bf(ldsW[kk * 260 + n]);
    char* chunk = (char*)wt + (size_t)blk * BCHUNK;
    unsigned swz = (unsigned)((n & 7) << 4);
    #pragma unroll
    for (int g = 0; g < 4; ++g)
      *(ushort8*)(chunk + (((unsigned)(n * 64 + g * 16)) ^ swz)) = *(ushort8*)&v[g * 8];
  }
}

// per-block histogram, deterministic (ballot-based, no atomics)
__global__ void bhist_k(const int* __restrict__ sp, int n, int* __restrict__ bc, int NE) {
  __shared__ int wc[4][16];
  int tid = threadIdx.x;
  int i = blockIdx.x * 256 + tid;
  int s = (i < n) ? sp[i] : -1;
  int w = tid >> 6, lane = tid & 63;
  for (int e = 0; e < NE; ++e) {
    unsigned long long m = __ballot(s == e);
    if (lane == 0) wc[w][e] = __popcll(m);
  }
  __syncthreads();
  if (tid < NE) bc[blockIdx.x * NE + tid] = wc[0][tid] + wc[1][tid] + wc[2][tid] + wc[3][tid];
}

// deterministic scan: blockCounts -> block offsets, species atom starts,
// species GROUP offsets, and gemm block->species partition.
__global__ void scan_k(const int* __restrict__ bc, int* __restrict__ bo,
                       int* __restrict__ atom_start, int* __restrict__ goff,
                       int* __restrict__ bstart, int nblocks, int NE) {
  __shared__ int csum[256];
  __shared__ int coff[256];
  __shared__ int stot[16];
  __shared__ int sbase[16];
  int tid = threadIdx.x;
  int per = (nblocks + CHUNKS - 1) / CHUNKS;
  int e = tid / CHUNKS, c = tid % CHUNKS;
  int b0 = c * per, b1 = b0 + per; if (b1 > nblocks) b1 = nblocks;
  if (tid < NE * CHUNKS) {
    int s = 0;
    for (int b = b0; b < b1; ++b) s += bc[b * NE + e];
    csum[tid] = s;
  }
  __syncthreads();
  if (tid < NE) {
    int r = 0;
    for (int c2 = 0; c2 < CHUNKS; ++c2) { coff[tid * CHUNKS + c2] = r; r += csum[tid * CHUNKS + c2]; }
    stot[tid] = r;
  }
  __syncthreads();
  if (tid == 0) {
    int a = 0, t = 0;
    for (int e2 = 0; e2 < NE; ++e2) {
      sbase[e2] = a;
      atom_start[e2] = a; goff[e2] = t;
      a += stot[e2]; t += (stot[e2] + GRP - 1) / GRP;
    }
    atom_start[NE] = a; goff[NE] = t;
    // partition NB_GEMM blocks across species proportional to groups, >=1
    int ntl = t > 0 ? t : 1;
    int nbk[16]; int tot = 0, emax = 0;
    for (int e2 = 0; e2 < NE; ++e2) {
      int nt = goff[e2 + 1] - goff[e2];
      int v = (nt > 0) ? (int)(((long long)nt * NB_GEMM) / ntl) : 0;
      if (nt > 0 && v < 1) v = 1;
      nbk[e2] = v; tot += v;
      if (nbk[e2] > nbk[emax]) emax = e2;
    }
    nbk[emax] += NB_GEMM - tot;
    int bacc = 0;
    for (int e2 = 0; e2 < NE; ++e2) { bstart[e2] = bacc; bacc += nbk[e2]; }
    bstart[NE] = bacc;
  }
  __syncthreads();
  if (tid < NE * CHUNKS) {
    int run = sbase[e] + coff[tid];
    for (int b = b0; b < b1; ++b) { bo[b * NE + e] = run; run += bc[b * NE + e]; }
  }
}

// deterministic scatter: rank = block-offset + wave-prefix + lane-prefix
__global__ void dscatter_k(const int* __restrict__ sp, int n, const int* __restrict__ bo,
                           int* __restrict__ sorted, int NE) {
  __shared__ int wc[4][16];
  int tid = threadIdx.x;
  int i = blockIdx.x * 256 + tid;
  int s = (i < n) ? sp[i] : -1;
  int w = tid >> 6, lane = tid & 63;
  for (int e = 0; e < NE; ++e) {
    unsigned long long m = __ballot(s == e);
    if (lane == 0) wc[w][e] = __popcll(m);
  }
  __syncthreads();
  for (int e = 0; e < NE; ++e) {
    unsigned long long m = __ballot(s == e);
    if (s == e) {
      int wpre = 0;
      for (int w2 = 0; w2 < 4; ++w2) if (w2 < w) wpre += wc[w2][e];
      int rank = __popcll(m & ((1ull << lane) - 1ull));
      sorted[bo[blockIdx.x * NE + e] + wpre + rank] = i;
    }
  }
}

// ---- barrier-free wave-autonomous fused GEMM + SiLU + layer2 ----------------

__global__ __launch_bounds__(512, 1) void gemm_k(
    const float* __restrict__ x, const unsigned short* __restrict__ wt,
    const float* __restrict__ b1, const float* __restrict__ w2,
    const float* __restrict__ b2, const int* __restrict__ sorted,
    const int* __restrict__ atom_start, const int* __restrict__ goff,
    const int* __restrict__ bstart, float* __restrict__ out, int NE)
{
  // LDS ~131 KB: full W1[e] bf16 (8 chunks x 16KB, swizzled image) + b1/w2.
  // 1 block/CU, 8 waves, ONE barrier total.
  __shared__ __align__(16) char ldsW[8 * BCHUNK];      // 128 KB
  __shared__ __align__(16) float b1s[NDIM], w2s[NDIM];
  __shared__ int goffs[17], astart[17], bst[17];

  int tid = threadIdx.x, lane = tid & 63, wid = tid >> 6;   // wid 0..7
  int lr = lane & 15, lg = lane >> 4;

  if (tid <= NE) {
    goffs[tid] = goff[tid]; astart[tid] = atom_start[tid]; bst[tid] = bstart[tid];
  }
  __syncthreads();

  // ---- block -> (species, group range) ----
  int b = blockIdx.x;
  int e = 0;
  while (b >= bst[e + 1]) ++e;
  int j = b - bst[e], nbe = bst[e + 1] - bst[e];
  int nge = goffs[e + 1] - goffs[e];
  int q = nge / nbe, r = nge % nbe;
  int gcnt = q + (j < r ? 1 : 0);
  if (gcnt <= 0) return;
  int g0 = j * q + (j < r ? j : r);          // first group within species
  int rs0 = astart[e] + g0 * GRP;            // first atom (sorted index)
  int aend = astart[e + 1];                  // exclusive end of species atoms

  // ---- W1[e] -> LDS (128 KB, linear copy of pre-swizzled image) ----
  {
    const char* wbase = (const char*)wt + (size_t)e * 8 * BCHUNK;
    #pragma unroll
    for (int i = 0; i < 16; ++i) {
      int off = (wid * 16 + i) * 1024;
      gload_lds16(wbase + off + lane * 16, ldsW + off);
    }
    if (tid < NDIM) {
      b1s[tid] = b1[(size_t)e * NDIM + tid];
      w2s[tid] = w2[(size_t)e * NDIM + tid];
    }
  }
  float b2v = b2[e];
  __syncthreads();   // drains W DMA + b1s/w2s; the ONLY barrier

  unsigned wswz = (unsigned)(lr * 64 + lg * 16) ^ ((unsigned)((lr & 7) << 4));

  // ---- grind: each wave owns groups wid, wid+8, ... ; fully independent ----
  for (int g = wid; g < gcnt; g += 8) {
    int aidx = rs0 + g * GRP + lr;
    if (aidx >= aend) aidx = aend - 1;       // tail: duplicate last atom (benign)
    int atom = sorted[aidx];
    const float* xp = x + (size_t)atom * NDIM + lg * 8;

    // x -> reg fragments, converted ONCE (32 VGPRs live)
    short8 af[8];
    #pragma unroll
    for (int s = 0; s < 8; ++s) {
      f32x4 lo = *(const f32x4*)(xp + s * 32);
      f32x4 hi = *(const f32x4*)(xp + s * 32 + 4);
      af[s] = cvt8(lo, hi);
    }

    // 128 ds_read_b128 + 128 swapped MFMAs; acc[16] = 64 VGPRs, static idx
    f32x4 acc[16];
    const f32x4 zero = {0.f, 0.f, 0.f, 0.f};
    #pragma unroll
    for (int nf = 0; nf < 16; ++nf) acc[nf] = zero;

    #pragma unroll
    for (int s = 0; s < 8; ++s) {
      const char* chunk = ldsW + s * BCHUNK;
      #pragma unroll
      for (int nf = 0; nf < 16; ++nf) {
        short8 wf = *(const short8*)(chunk + nf * 1024 + wswz);
        acc[nf] = __builtin_amdgcn_mfma_f32_16x16x32_bf16(wf, af[s], acc[nf], 0, 0, 0);
      }
    }

    // epilogue: lane holds D[n = nf*16 + lg*4 + rg][atom (col lr)]
    float sacc = 0.f;
    #pragma unroll
    for (int nf = 0; nf < 16; ++nf) {
      f32x4 bb = *(const f32x4*)&b1s[nf * 16 + lg * 4];
      f32x4 wv = *(const f32x4*)&w2s[nf * 16 + lg * 4];
      #pragma unroll
      for (int rg = 0; rg < 4; ++rg) {
        float h = acc[nf][rg] + bb[rg];
        sacc += h * __builtin_amdgcn_rcpf(1.f + __expf(-h)) * wv[rg];
      }
    }
    sacc += __shfl_xor(sacc, 16, 64);
    sacc += __shfl_xor(sacc, 32, 64);
    if (lg == 0) out[atom] = sacc + b2v;     // tail dups store identical value
  }
}

// ---- launch -----------------------------------------------------------------

extern "C" void kernel_launch(void* const* d_in, const int* in_sizes, int n_in,
                              void* d_out, int out_size, void* d_ws, size_t ws_size,
                              hipStream_t stream) {
  const float* x  = (const float*)d_in[0];
  const int*   sp = (const int*)d_in[1];
  const float* W1 = (const float*)d_in[2];
  const float* b1 = (const float*)d_in[3];
  const float* W2 = (const float*)d_in[4];
  const float* b2 = (const float*)d_in[5];
  float* out = (float*)d_out;

  int n_atoms = in_sizes[0] / NDIM;
  int NE = in_sizes[2] / (NDIM * NDIM);
  int nblocks = (n_atoms + 255) / 256;

  // workspace layout (all 256-aligned); every word read is written this call.
  char* wsb = (char*)d_ws;
  size_t o = 0;
  int* bc = (int*)(wsb + o);         o += ((size_t)nblocks * NE * 4 + 255) & ~(size_t)255;
  int* bo = (int*)(wsb + o);         o += ((size_t)nblocks * NE * 4 + 255) & ~(size_t)255;
  int* atom_start = (int*)(wsb + o); o += 256;
  int* goff       = (int*)(wsb + o); o += 256;
  int* bstart     = (int*)(wsb + o); o += 256;
  int* sorted     = (int*)(wsb + o); o += ((size_t)n_atoms * 4 + 255) & ~(size_t)255;
  unsigned short* wt = (unsigned short*)(wsb + o);   // NE*128KB, 256-aligned

  hipLaunchKernelGGL(convw_k, dim3(NE * 8), dim3(256), 0, stream, W1, wt, NE);
  hipLaunchKernelGGL(bhist_k, dim3(nblocks), dim3(256), 0, stream, sp, n_atoms, bc, NE);
  hipLaunchKernelGGL(scan_k, dim3(1), dim3(256), 0, stream, bc, bo, atom_start, goff,
                     bstart, nblocks, NE);
  hipLaunchKernelGGL(dscatter_k, dim3(nblocks), dim3(256), 0, stream, sp, n_atoms, bo,
                     sorted, NE);

  hipLaunchKernelGGL(gemm_k, dim3(NB_GEMM), dim3(512), 0, stream,
                     x, wt, b1, W2, b2, sorted, atom_start, goff, bstart, out, NE);
}

// Round 18
// 62.209 us; speedup vs baseline: 5.2940x; 5.2940x over previous
//
#include <hip/hip_runtime.h>
#include <hip/hip_bf16.h>
#include <stdint.h>

// ElementReadoutMLP: species-routed 2-layer MLP, fused.
// r18: wave-autonomous gemm, SPILL-PROOF BY CONSTRUCTION.
// r13/r14/r17 all spilled (FETCH 270-440MB) because the unrolled 8x16
// ds_read+MFMA loop let the scheduler hoist dozens of W-frag loads ->
// live pressure >> cap.  r18: (a) acc halved to acc[8] via two nf-half
// passes, (b) sched_barrier(0) fences at every K-step so at most one
// 8-read wf batch is in flight.  Worst-case live ~120 VGPR.
//   bhist_k / scan_k / dscatter_k : countsort atoms by species;
//     scan_k partitions gemm blocks across species by 16-atom GROUPS.
//   convw_k : W1 -> pre-swizzled bf16 wt (LDS-image layout, coalesced)
//   gemm_k  : 256 blocks x 512 thr, ONE species per block.  Whole W1[e]
//             (128KB bf16) -> LDS once; ONE barrier; each wave then
//             independently grinds 16-atom groups: x -> reg frags (cvt
//             once), fenced ds_read_b128 + swapped MFMA (D[n][atom]),
//             in-lane SiLU+w2 fold, 2 shfl_xor, store.

#define NDIM 256
#define CHUNKS 16      // scan chunks per species (NE*CHUNKS <= 256)
#define BCHUNK 16384   // bytes per W k-chunk (256 n x 32 k x 2B)
#define GRP 16         // atoms per group (one wave-iteration)
#define NB_GEMM 256    // persistent gemm grid (1 block/CU)

typedef __attribute__((ext_vector_type(8))) short short8;
typedef __attribute__((ext_vector_type(8))) unsigned short ushort8;
typedef __attribute__((ext_vector_type(4))) float f32x4;

__device__ __forceinline__ unsigned short f2bf(float f) {
  unsigned u = __float_as_uint(f);
  u = (u + 0x7FFFu + ((u >> 16) & 1u)) >> 16;   // round-to-nearest-even
  return (unsigned short)u;
}

// async global->LDS, 16B per lane; lds dest wave-uniform base (+lane*16 HW).
__device__ __forceinline__ void gload_lds16(const void* gsrc, void* ldst) {
  __builtin_amdgcn_global_load_lds(
      (const __attribute__((address_space(1))) unsigned*)gsrc,
      (__attribute__((address_space(3))) unsigned*)(uintptr_t)(unsigned)(uintptr_t)ldst,
      16, 0, 0);
}

// pack 8 fp32 -> short8 of bf16 (RNE, packed cvt)
__device__ __forceinline__ short8 cvt8(f32x4 lo, f32x4 hi) {
  union { short8 s; unsigned u[4]; } r;
  __hip_bfloat162 t;
  t = __float22bfloat162_rn(make_float2(lo[0], lo[1])); r.u[0] = *(unsigned*)&t;
  t = __float22bfloat162_rn(make_float2(lo[2], lo[3])); r.u[1] = *(unsigned*)&t;
  t = __float22bfloat162_rn(make_float2(hi[0], hi[1])); r.u[2] = *(unsigned*)&t;
  t = __float22bfloat162_rn(make_float2(hi[2], hi[3])); r.u[3] = *(unsigned*)&t;
  return r.s;
}

// ---- prep kernels -----------------------------------------------------------

// wt layout: chunk(e,step) = wt + (e*8+step)*BCHUNK bytes; within chunk,
// bf16 for (n,kk) at byte ((n*64 + kk*2) ^ ((n&7)<<4)).  Linear copy into
// LDS reproduces the swizzled layout gemm_k's ds_reads expect (rule #21).
__global__ void convw_k(const float* __restrict__ W1, unsigned short* __restrict__ wt, int NE) {
  __shared__ float ldsW[32 * 260];   // 32 k-rows x 256 n, padded
  int blk = blockIdx.x;              // e*8 + step
  int e = blk >> 3, step = blk & 7;
  int tid = threadIdx.x;
  int k0 = step * 32;
  {
    int kk = tid >> 3, part = tid & 7;
    const float* src = W1 + ((size_t)e << 16) + (size_t)(k0 + kk) * NDIM + part * 32;
    #pragma unroll
    for (int j = 0; j < 8; ++j) {
      f32x4 v = *(const f32x4*)(src + j * 4);
      *(f32x4*)&ldsW[kk * 260 + part * 32 + j * 4] = v;
    }
  }
  __syncthreads();
  {
    int n = tid;
    unsigned short v[32];
    #pragma unroll
    for (int kk = 0; kk < 32; ++kk) v[kk] = f2bf(ldsW[kk * 260 + n]);
    char* chunk = (char*)wt + (size_t)blk * BCHUNK;
    unsigned swz = (unsigned)((n & 7) << 4);
    #pragma unroll
    for (int g = 0; g < 4; ++g)
      *(ushort8*)(chunk + (((unsigned)(n * 64 + g * 16)) ^ swz)) = *(ushort8*)&v[g * 8];
  }
}

// per-block histogram, deterministic (ballot-based, no atomics)
__global__ void bhist_k(const int* __restrict__ sp, int n, int* __restrict__ bc, int NE) {
  __shared__ int wc[4][16];
  int tid = threadIdx.x;
  int i = blockIdx.x * 256 + tid;
  int s = (i < n) ? sp[i] : -1;
  int w = tid >> 6, lane = tid & 63;
  for (int e = 0; e < NE; ++e) {
    unsigned long long m = __ballot(s == e);
    if (lane == 0) wc[w][e] = __popcll(m);
  }
  __syncthreads();
  if (tid < NE) bc[blockIdx.x * NE + tid] = wc[0][tid] + wc[1][tid] + wc[2][tid] + wc[3][tid];
}

// deterministic scan: blockCounts -> block offsets, species atom starts,
// species GROUP offsets, and gemm block->species partition.
__global__ void scan_k(const int* __restrict__ bc, int* __restrict__ bo,
                       int* __restrict__ atom_start, int* __restrict__ goff,
                       int* __restrict__ bstart, int nblocks, int NE) {
  __shared__ int csum[256];
  __shared__ int coff[256];
  __shared__ int stot[16];
  __shared__ int sbase[16];
  int tid = threadIdx.x;
  int per = (nblocks + CHUNKS - 1) / CHUNKS;
  int e = tid / CHUNKS, c = tid % CHUNKS;
  int b0 = c * per, b1 = b0 + per; if (b1 > nblocks) b1 = nblocks;
  if (tid < NE * CHUNKS) {
    int s = 0;
    for (int b = b0; b < b1; ++b) s += bc[b * NE + e];
    csum[tid] = s;
  }
  __syncthreads();
  if (tid < NE) {
    int r = 0;
    for (int c2 = 0; c2 < CHUNKS; ++c2) { coff[tid * CHUNKS + c2] = r; r += csum[tid * CHUNKS + c2]; }
    stot[tid] = r;
  }
  __syncthreads();
  if (tid == 0) {
    int a = 0, t = 0;
    for (int e2 = 0; e2 < NE; ++e2) {
      sbase[e2] = a;
      atom_start[e2] = a; goff[e2] = t;
      a += stot[e2]; t += (stot[e2] + GRP - 1) / GRP;
    }
    atom_start[NE] = a; goff[NE] = t;
    // partition NB_GEMM blocks across species proportional to groups, >=1
    int ntl = t > 0 ? t : 1;
    int nbk[16]; int tot = 0, emax = 0;
    for (int e2 = 0; e2 < NE; ++e2) {
      int nt = goff[e2 + 1] - goff[e2];
      int v = (nt > 0) ? (int)(((long long)nt * NB_GEMM) / ntl) : 0;
      if (nt > 0 && v < 1) v = 1;
      nbk[e2] = v; tot += v;
      if (nbk[e2] > nbk[emax]) emax = e2;
    }
    nbk[emax] += NB_GEMM - tot;
    int bacc = 0;
    for (int e2 = 0; e2 < NE; ++e2) { bstart[e2] = bacc; bacc += nbk[e2]; }
    bstart[NE] = bacc;
  }
  __syncthreads();
  if (tid < NE * CHUNKS) {
    int run = sbase[e] + coff[tid];
    for (int b = b0; b < b1; ++b) { bo[b * NE + e] = run; run += bc[b * NE + e]; }
  }
}

// deterministic scatter: rank = block-offset + wave-prefix + lane-prefix
__global__ void dscatter_k(const int* __restrict__ sp, int n, const int* __restrict__ bo,
                           int* __restrict__ sorted, int NE) {
  __shared__ int wc[4][16];
  int tid = threadIdx.x;
  int i = blockIdx.x * 256 + tid;
  int s = (i < n) ? sp[i] : -1;
  int w = tid >> 6, lane = tid & 63;
  for (int e = 0; e < NE; ++e) {
    unsigned long long m = __ballot(s == e);
    if (lane == 0) wc[w][e] = __popcll(m);
  }
  __syncthreads();
  for (int e = 0; e < NE; ++e) {
    unsigned long long m = __ballot(s == e);
    if (s == e) {
      int wpre = 0;
      for (int w2 = 0; w2 < 4; ++w2) if (w2 < w) wpre += wc[w2][e];
      int rank = __popcll(m & ((1ull << lane) - 1ull));
      sorted[bo[blockIdx.x * NE + e] + wpre + rank] = i;
    }
  }
}

// ---- barrier-free wave-autonomous fused GEMM + SiLU + layer2 ----------------

__global__ __launch_bounds__(512, 2) void gemm_k(
    const float* __restrict__ x, const unsigned short* __restrict__ wt,
    const float* __restrict__ b1, const float* __restrict__ w2,
    const float* __restrict__ b2, const int* __restrict__ sorted,
    const int* __restrict__ atom_start, const int* __restrict__ goff,
    const int* __restrict__ bstart, float* __restrict__ out, int NE)
{
  // LDS ~131 KB: full W1[e] bf16 (8 chunks x 16KB, swizzled image) + b1/w2.
  // 1 block/CU, 8 waves, ONE barrier total.
  __shared__ __align__(16) char ldsW[8 * BCHUNK];      // 128 KB
  __shared__ __align__(16) float b1s[NDIM], w2s[NDIM];
  __shared__ int goffs[17], astart[17], bst[17];

  int tid = threadIdx.x, lane = tid & 63, wid = tid >> 6;   // wid 0..7
  int lr = lane & 15, lg = lane >> 4;

  if (tid <= NE) {
    goffs[tid] = goff[tid]; astart[tid] = atom_start[tid]; bst[tid] = bstart[tid];
  }
  __syncthreads();

  // ---- block -> (species, group range) ----
  int b = blockIdx.x;
  int e = 0;
  while (b >= bst[e + 1]) ++e;
  int j = b - bst[e], nbe = bst[e + 1] - bst[e];
  int nge = goffs[e + 1] - goffs[e];
  int q = nge / nbe, r = nge % nbe;
  int gcnt = q + (j < r ? 1 : 0);
  if (gcnt <= 0) return;
  int g0 = j * q + (j < r ? j : r);          // first group within species
  int rs0 = astart[e] + g0 * GRP;            // first atom (sorted index)
  int aend = astart[e + 1];                  // exclusive end of species atoms

  // ---- W1[e] -> LDS (128 KB, linear copy of pre-swizzled image) ----
  {
    const char* wbase = (const char*)wt + (size_t)e * 8 * BCHUNK;
    #pragma unroll
    for (int i = 0; i < 16; ++i) {
      int off = (wid * 16 + i) * 1024;
      gload_lds16(wbase + off + lane * 16, ldsW + off);
    }
    if (tid < NDIM) {
      b1s[tid] = b1[(size_t)e * NDIM + tid];
      w2s[tid] = w2[(size_t)e * NDIM + tid];
    }
  }
  float b2v = b2[e];
  __syncthreads();   // drains W DMA + b1s/w2s; the ONLY barrier

  unsigned wswz = (unsigned)(lr * 64 + lg * 16) ^ ((unsigned)((lr & 7) << 4));

  // ---- grind: each wave owns groups wid, wid+8, ... ; fully independent ----
  for (int g = wid; g < gcnt; g += 8) {
    int aidx = rs0 + g * GRP + lr;
    if (aidx >= aend) aidx = aend - 1;       // tail: duplicate last atom (benign)
    int atom = sorted[aidx];
    const float* xp = x + (size_t)atom * NDIM + lg * 8;

    // x -> reg fragments, converted ONCE (32 VGPRs live)
    short8 af[8];
    #pragma unroll
    for (int s = 0; s < 8; ++s) {
      f32x4 lo = *(const f32x4*)(xp + s * 32);
      f32x4 hi = *(const f32x4*)(xp + s * 32 + 4);
      af[s] = cvt8(lo, hi);
    }

    float sacc = 0.f;
    // two nf-half passes: acc[8] (32 VGPRs) live per pass; wf batches of 8
    // (32 VGPRs) fenced by sched_barrier so the scheduler cannot hoist
    // later batches (the r13/r14/r17 spill mechanism).
    #pragma unroll
    for (int h = 0; h < 2; ++h) {
      f32x4 acc[8];
      const f32x4 zero = {0.f, 0.f, 0.f, 0.f};
      #pragma unroll
      for (int nf = 0; nf < 8; ++nf) acc[nf] = zero;

      #pragma unroll
      for (int s = 0; s < 8; ++s) {
        __builtin_amdgcn_sched_barrier(0);   // fence: one wf batch in flight
        short8 wf[8];
        #pragma unroll
        for (int nf = 0; nf < 8; ++nf)
          wf[nf] = *(const short8*)(ldsW + s * BCHUNK + (h * 8 + nf) * 1024 + wswz);
        #pragma unroll
        for (int nf = 0; nf < 8; ++nf)
          acc[nf] = __builtin_amdgcn_mfma_f32_16x16x32_bf16(wf[nf], af[s], acc[nf], 0, 0, 0);
      }
      __builtin_amdgcn_sched_barrier(0);

      // fold this half's acc into the running scalar (frees acc regs)
      #pragma unroll
      for (int nf = 0; nf < 8; ++nf) {
        int n0 = (h * 8 + nf) * 16 + lg * 4;
        f32x4 bb = *(const f32x4*)&b1s[n0];
        f32x4 wv = *(const f32x4*)&w2s[n0];
        #pragma unroll
        for (int rg = 0; rg < 4; ++rg) {
          float hh = acc[nf][rg] + bb[rg];
          sacc += hh * __builtin_amdgcn_rcpf(1.f + __expf(-hh)) * wv[rg];
        }
      }
    }

    sacc += __shfl_xor(sacc, 16, 64);
    sacc += __shfl_xor(sacc, 32, 64);
    if (lg == 0) out[atom] = sacc + b2v;     // tail dups store identical value
  }
}

// ---- launch -----------------------------------------------------------------

extern "C" void kernel_launch(void* const* d_in, const int* in_sizes, int n_in,
                              void* d_out, int out_size, void* d_ws, size_t ws_size,
                              hipStream_t stream) {
  const float* x  = (const float*)d_in[0];
  const int*   sp = (const int*)d_in[1];
  const float* W1 = (const float*)d_in[2];
  const float* b1 = (const float*)d_in[3];
  const float* W2 = (const float*)d_in[4];
  const float* b2 = (const float*)d_in[5];
  float* out = (float*)d_out;

  int n_atoms = in_sizes[0] / NDIM;
  int NE = in_sizes[2] / (NDIM * NDIM);
  int nblocks = (n_atoms + 255) / 256;

  // workspace layout (all 256-aligned); every word read is written this call.
  char* wsb = (char*)d_ws;
  size_t o = 0;
  int* bc = (int*)(wsb + o);         o += ((size_t)nblocks * NE * 4 + 255) & ~(size_t)255;
  int* bo = (int*)(wsb + o);         o += ((size_t)nblocks * NE * 4 + 255) & ~(size_t)255;
  int* atom_start = (int*)(wsb + o); o += 256;
  int* goff       = (int*)(wsb + o); o += 256;
  int* bstart     = (int*)(wsb + o); o += 256;
  int* sorted     = (int*)(wsb + o); o += ((size_t)n_atoms * 4 + 255) & ~(size_t)255;
  unsigned short* wt = (unsigned short*)(wsb + o);   // NE*128KB, 256-aligned

  hipLaunchKernelGGL(convw_k, dim3(NE * 8), dim3(256), 0, stream, W1, wt, NE);
  hipLaunchKernelGGL(bhist_k, dim3(nblocks), dim3(256), 0, stream, sp, n_atoms, bc, NE);
  hipLaunchKernelGGL(scan_k, dim3(1), dim3(256), 0, stream, bc, bo, atom_start, goff,
                     bstart, nblocks, NE);
  hipLaunchKernelGGL(dscatter_k, dim3(nblocks), dim3(256), 0, stream, sp, n_atoms, bo,
                     sorted, NE);

  hipLaunchKernelGGL(gemm_k, dim3(NB_GEMM), dim3(512), 0, stream,
                     x, wt, b1, W2, b2, sorted, atom_start, goff, bstart, out, NE);
}